// Round 8
// baseline (227.463 us; speedup 1.0000x reference)
//
#include <hip/hip_runtime.h>

#define T_TOK 16384
#define H_DIM 4096
#define O_DIM 4096
#define NA 8
#define RANK 16

typedef float f32x4 __attribute__((ext_vector_type(4)));
typedef short bf16x8 __attribute__((ext_vector_type(8)));

// f32 -> bf16 (RTNE)
static __device__ __forceinline__ unsigned short f2bf(float f) {
    unsigned int u = __float_as_uint(f);
    u = (u + 0x7fffu + ((u >> 16) & 1u)) >> 16;
    return (unsigned short)u;
}

// ---------------- sort-by-adapter machinery ----------------

__global__ void k_zero(int* __restrict__ counts) {
    if (threadIdx.x < NA) counts[threadIdx.x] = 0;
}

__global__ void k_hist(const int* __restrict__ idx, int* __restrict__ counts) {
    __shared__ int h[NA];
    if (threadIdx.x < NA) h[threadIdx.x] = 0;
    __syncthreads();
    int t = blockIdx.x * blockDim.x + threadIdx.x;
    atomicAdd(&h[idx[t]], 1);
    __syncthreads();
    if (threadIdx.x < NA) atomicAdd(&counts[threadIdx.x], h[threadIdx.x]);
}

__global__ void k_prefix(const int* __restrict__ counts, int* __restrict__ offs,
                         int* __restrict__ cursor) {
    if (threadIdx.x == 0) {
        int run = 0;
        for (int n = 0; n < NA; n++) { offs[n] = run; cursor[n] = run; run += counts[n]; }
    }
}

__global__ void k_scatter(const int* __restrict__ idx, int* __restrict__ cursor,
                          int* __restrict__ order) {
    int t = blockIdx.x * blockDim.x + threadIdx.x;
    int a = idx[t];
    int lane = threadIdx.x & 63;
    for (int n = 0; n < NA; n++) {
        unsigned long long m = __ballot(a == n);
        if (m) {
            int leader = __ffsll((unsigned long long)m) - 1;
            int cnt = __popcll(m);
            int base = 0;
            if (lane == leader) base = atomicAdd(&cursor[n], cnt);
            base = __shfl(base, leader);
            if (a == n) {
                int rank = __popcll(m & ((1ull << lane) - 1ull));
                order[base + rank] = t;
            }
        }
    }
}

// ---------------- transpose A -> ATb[n][r][h] (bf16) ----------------

__global__ void k_transpose(const float* __restrict__ A, unsigned short* __restrict__ ATb) {
    const int n = blockIdx.y;
    const int h0 = blockIdx.x * 256;
    __shared__ float lds[256 * 17];
    const float4* src = (const float4*)(A + ((size_t)n * H_DIM + h0) * RANK);
#pragma unroll
    for (int k = 0; k < 4; ++k) {
        int f = k * 256 + threadIdx.x;
        float4 v = src[f];
        int row = (f * 4) >> 4, col = (f * 4) & 15;
        lds[row * 17 + col + 0] = v.x;
        lds[row * 17 + col + 1] = v.y;
        lds[row * 17 + col + 2] = v.z;
        lds[row * 17 + col + 3] = v.w;
    }
    __syncthreads();
    unsigned short* dst = ATb + (size_t)n * RANK * H_DIM;
#pragma unroll
    for (int r = 0; r < RANK; ++r)
        dst[(size_t)r * H_DIM + h0 + threadIdx.x] = f2bf(lds[threadIdx.x * 17 + r]);
}

// ---------------- fused: per 16-token tile, shrink (MFMA) then expand ----------------
// Phase 1: wave w = K-quarter of [16 x 4096]@[4096 x 16] -> vp[w] in LDS -> vsum.
// Phase 2: 4 col-quarters; B slice PINNED in 64 VGPR (asm anchor); 3-deep NT
// prefetch on result rows; NT store to out.

__global__ __launch_bounds__(256, 3) void k_fused(
    const float* __restrict__ result, const float* __restrict__ x,
    const unsigned short* __restrict__ atb, const float* __restrict__ lora_b,
    const int* __restrict__ order, const int* __restrict__ counts,
    const int* __restrict__ offs, float* __restrict__ out) {

    // block -> (adapter n, tile)
    const int bid = blockIdx.x;
    int n = 0, tile = 0, found = 0, acc_t = 0;
#pragma unroll
    for (int i = 0; i < NA; ++i) {
        int tn = (counts[i] + 15) >> 4;
        if (!found && bid < acc_t + tn) { n = i; tile = bid - acc_t; found = 1; }
        acc_t += tn;
    }
    if (!found) return;
    const int cnt = counts[n];
    const int seg = offs[n];
    const int tbase = tile << 4;
    const int np = min(16, cnt - tbase);

    __shared__ float vp[4][16][16];
    __shared__ float vsum[16][16];
    __shared__ int toks[16];

    const int w = threadIdx.x >> 6, lane = threadIdx.x & 63;
    const int mi = lane & 15, kg = lane >> 4;

    if (threadIdx.x < 16)
        toks[threadIdx.x] = order[seg + min(tbase + (int)threadIdx.x, cnt - 1)];

    // ---- phase 1: shrink quarter kc = w ----
    {
        const int tokm = order[seg + min(tbase + mi, cnt - 1)];
        const float* xp = x + (size_t)tokm * H_DIM + w * 1024 + kg * 8;
        const unsigned short* bp0 = atb + ((size_t)n * RANK + mi) * H_DIM + w * 1024 + kg * 8;

        f32x4 acc = {0.f, 0.f, 0.f, 0.f};
#pragma unroll 8
        for (int ks = 0; ks < 32; ++ks) {
            f32x4 xlo = *(const f32x4*)(xp + ks * 32);
            f32x4 xhi = *(const f32x4*)(xp + ks * 32 + 4);
            bf16x8 bfrag = *(const bf16x8*)(bp0 + ks * 32);
            bf16x8 afrag;
            afrag[0] = (short)f2bf(xlo.x); afrag[1] = (short)f2bf(xlo.y);
            afrag[2] = (short)f2bf(xlo.z); afrag[3] = (short)f2bf(xlo.w);
            afrag[4] = (short)f2bf(xhi.x); afrag[5] = (short)f2bf(xhi.y);
            afrag[6] = (short)f2bf(xhi.z); afrag[7] = (short)f2bf(xhi.w);
            acc = __builtin_amdgcn_mfma_f32_16x16x32_bf16(afrag, bfrag, acc, 0, 0, 0);
        }
#pragma unroll
        for (int q = 0; q < 4; ++q)
            vp[w][kg * 4 + q][mi] = acc[q];
    }
    __syncthreads();
    {
        const int p = threadIdx.x >> 4, r = threadIdx.x & 15;
        vsum[p][r] = (vp[0][p][r] + vp[1][p][r]) + (vp[2][p][r] + vp[3][p][r]);
    }
    __syncthreads();

    // ---- phase 2: expand 4 col-quarters ----
    const float* Bn = lora_b + (size_t)n * RANK * O_DIM;
#pragma unroll 1
    for (int q = 0; q < 4; ++q) {
        const int o0 = q * 1024 + (threadIdx.x << 2);
        f32x4 b[RANK];
#pragma unroll
        for (int r = 0; r < RANK; ++r)
            b[r] = *(const f32x4*)(Bn + (size_t)r * O_DIM + o0);
        // pin the B slice in VGPRs — forbid rematerialization inside the p-loop
#pragma unroll
        for (int r = 0; r < RANK; ++r)
            asm volatile("" : "+v"(b[r]));

        // 3-deep rotation prefetch of result rows
        size_t offA = (size_t)toks[0] * O_DIM + o0;
        f32x4 rA = __builtin_nontemporal_load((const f32x4*)(result + offA));
        size_t offB = offA, offC = offA;
        f32x4 rB = rA, rC = rA;
        if (np > 1) {
            offB = (size_t)toks[1] * O_DIM + o0;
            rB = __builtin_nontemporal_load((const f32x4*)(result + offB));
        }
        if (np > 2) {
            offC = (size_t)toks[2] * O_DIM + o0;
            rC = __builtin_nontemporal_load((const f32x4*)(result + offC));
        }

        for (int p = 0; p < np; ++p) {
            f32x4 rD = rC;
            size_t offD = 0;
            if (p + 3 < np) {
                offD = (size_t)toks[p + 3] * O_DIM + o0;
                rD = __builtin_nontemporal_load((const f32x4*)(result + offD));
            }
            float va[RANK];
#pragma unroll
            for (int u = 0; u < 4; ++u)
                *(f32x4*)&va[u * 4] = *(const f32x4*)&vsum[p][u * 4];
            f32x4 acc = rA;
#pragma unroll
            for (int r = 0; r < RANK; ++r) {
                acc.x = fmaf(va[r], b[r].x, acc.x);
                acc.y = fmaf(va[r], b[r].y, acc.y);
                acc.z = fmaf(va[r], b[r].z, acc.z);
                acc.w = fmaf(va[r], b[r].w, acc.w);
            }
            __builtin_nontemporal_store(acc, (f32x4*)(out + offA));
            rA = rB; offA = offB;
            rB = rC; offB = offC;
            rC = rD; offC = offD;
        }
    }
}

// ---------------- launch ----------------

extern "C" void kernel_launch(void* const* d_in, const int* in_sizes, int n_in,
                              void* d_out, int out_size, void* d_ws, size_t ws_size,
                              hipStream_t stream) {
    const float* result = (const float*)d_in[0];
    const float* x      = (const float*)d_in[1];
    const float* lora_a = (const float*)d_in[2];
    const float* lora_b = (const float*)d_in[3];
    const int*   aidx   = (const int*)d_in[4];
    float* out = (float*)d_out;

    int* order  = (int*)d_ws;
    int* counts = order + T_TOK;
    int* offs   = counts + NA;
    int* cursor = offs + NA;
    unsigned short* ATb = (unsigned short*)(cursor + NA);        // 1 MB

    k_zero<<<dim3(1), dim3(64), 0, stream>>>(counts);
    k_hist<<<dim3(64), dim3(256), 0, stream>>>(aidx, counts);
    k_prefix<<<dim3(1), dim3(64), 0, stream>>>(counts, offs, cursor);
    k_scatter<<<dim3(64), dim3(256), 0, stream>>>(aidx, cursor, order);
    k_transpose<<<dim3(16, NA), dim3(256), 0, stream>>>(lora_a, ATb);
    k_fused<<<dim3(T_TOK / 16 + NA), dim3(256), 0, stream>>>(
        result, x, ATb, lora_b, order, counts, offs, out);
}